// Round 14
// baseline (150.279 us; speedup 1.0000x reference)
//
#include <hip/hip_runtime.h>
#include <hip/hip_bf16.h>
#include <cstddef>

#define FG 6
#define L 1024
#define NB 768
#define MN 8
#define H 16
#define HD 64
#define ADIM 1024
#define STAGES 4
#define SCALE 0.125f

typedef __attribute__((ext_vector_type(8))) short bf16x8;
typedef __attribute__((ext_vector_type(4))) float f32x4;
typedef __attribute__((address_space(3))) short lds_short_t;
typedef const __attribute__((address_space(1))) short g_short_t;

__device__ __forceinline__ int clampi(int v, int lo, int hi) {
  return v < lo ? lo : (v > hi ? hi : v);
}

__device__ __forceinline__ short f2bf(float f) {
  __hip_bfloat16 h = __float2bfloat16(f);
  return *reinterpret_cast<short*>(&h);
}

__device__ __forceinline__ float bf2f(short s) {
  __hip_bfloat16 h = *reinterpret_cast<__hip_bfloat16*>(&s);
  return __bfloat162float(h);
}

__device__ __forceinline__ void gload16(const short* g, short* l) {
  __builtin_amdgcn_global_load_lds((g_short_t*)g, (lds_short_t*)l, 16, 0, 0);
}

// One dispatch: blocks [0,12288) zero d_out (blocks <6144 also convert x to
// bf16); blocks [12288,15360) transpose qkv_w; [15360,16384) transpose out_w.
__global__ __launch_bounds__(256)
void prep_kernel(const float* __restrict__ x, short* __restrict__ xb,
                 float* __restrict__ zout,
                 const float* __restrict__ qkv_w, short* __restrict__ qwT,
                 const float* __restrict__ out_w, short* __restrict__ owT) {
  const int b = blockIdx.x;
  if (b < 12288) {
    const size_t zi = ((size_t)b * 256 + threadIdx.x) * 4;
    *(float4*)(zout + zi) = (float4){0.f, 0.f, 0.f, 0.f};
    if (b >= 6144) return;
    size_t i = ((size_t)b * 256 + threadIdx.x) * 8;
    float4 a = *(const float4*)(x + i);
    float4 c = *(const float4*)(x + i + 4);
    bf16x8 v;
    v[0] = f2bf(a.x); v[1] = f2bf(a.y); v[2] = f2bf(a.z); v[3] = f2bf(a.w);
    v[4] = f2bf(c.x); v[5] = f2bf(c.y); v[6] = f2bf(c.z); v[7] = f2bf(c.w);
    *(bf16x8*)(xb + i) = v;
    return;
  }
  int t = b - 12288;
  const float* in; short* out; int N, n0, k0;
  if (t < 3072) { in = qkv_w; out = qwT; N = 3072; n0 = (t % 96) * 32; k0 = (t / 96) * 32; }
  else { t -= 3072; in = out_w; out = owT; N = 1024; n0 = (t % 32) * 32; k0 = (t / 32) * 32; }
  __shared__ float tile[32][33];
  const int tx = threadIdx.x & 31, ty = threadIdx.x >> 5;
  #pragma unroll
  for (int i = 0; i < 4; ++i)
    tile[ty + i * 8][tx] = in[(size_t)(k0 + ty + i * 8) * N + n0 + tx];
  __syncthreads();
  #pragma unroll
  for (int i = 0; i < 4; ++i)
    out[(size_t)(n0 + ty + i * 8) * 1024 + k0 + tx] =
        f2bf(tile[tx][ty + i * 8]);
}

// ============ 64x128 m97-structure Q-GEMM (192 blocks, proven r8) =========
__global__ __launch_bounds__(256)
void q_gemm64(const short* __restrict__ A, const short* __restrict__ B,
              float* __restrict__ C,
              const int* __restrict__ f_ids, const int* __restrict__ t_ids)
{
  __shared__ __align__(16) short As[4096];    // 64 x 64
  __shared__ __align__(16) short Bs[8192];    // 128 x 64

  const int tid = threadIdx.x;
  const int w = tid >> 6, lane = tid & 63;
  const int row0 = blockIdx.y * 64, col0 = blockIdx.x * 128;
  const int lr = lane & 15, lq = lane >> 4;
  const int wrow = (w >> 1) * 32, wcol = (w & 1) * 64;

  size_t asrc[2]; short* adst[2];
  #pragma unroll
  for (int c = 0; c < 2; ++c) {
    const int d = c * 256 + tid, r = d >> 3;
    const int ss = (d & 7) ^ (r & 7);
    const int rr = row0 + r;
    const int bi = rr >= NB;
    const int idx = rr - bi * NB;
    const int f = clampi(f_ids[idx], 0, FG - 1);
    const int q = clampi(t_ids[idx], 0, L - 1);
    asrc[c] = (size_t)((bi * FG + f) * L + q) * 1024 + ss * 8;
    adst[c] = As + d * 8;
  }
  size_t bsrc[4]; short* bdst[4];
  #pragma unroll
  for (int c = 0; c < 4; ++c) {
    const int d = c * 256 + tid, r = d >> 3;
    const int ss = (d & 7) ^ (r & 7);
    bsrc[c] = (size_t)(col0 + r) * 1024 + ss * 8;
    bdst[c] = Bs + d * 8;
  }

  const char* As8 = (const char*)As;
  const char* Bs8 = (const char*)Bs;
  const int swz = lr & 7;

  f32x4 acc[2][4];
  #pragma unroll
  for (int m = 0; m < 2; ++m)
    #pragma unroll
    for (int n = 0; n < 4; ++n) acc[m][n] = (f32x4){0.f, 0.f, 0.f, 0.f};

  for (int kt = 0; kt < 16; ++kt) {
    #pragma unroll
    for (int c = 0; c < 2; ++c) gload16(A + asrc[c] + kt * 64, adst[c]);
    #pragma unroll
    for (int c = 0; c < 4; ++c) gload16(B + bsrc[c] + kt * 64, bdst[c]);
    __syncthreads();
    #pragma unroll
    for (int kk = 0; kk < 2; ++kk) {
      const int so = ((kk * 4 + lq) ^ swz) << 4;
      bf16x8 av[2], bv[4];
      #pragma unroll
      for (int m = 0; m < 2; ++m)
        av[m] = *(const bf16x8*)(As8 + (wrow + m * 16 + lr) * 128 + so);
      #pragma unroll
      for (int n = 0; n < 4; ++n)
        bv[n] = *(const bf16x8*)(Bs8 + (wcol + n * 16 + lr) * 128 + so);
      #pragma unroll
      for (int m = 0; m < 2; ++m)
        #pragma unroll
        for (int n = 0; n < 4; ++n)
          acc[m][n] = __builtin_amdgcn_mfma_f32_16x16x32_bf16(
              av[m], bv[n], acc[m][n], 0, 0, 0);
    }
    __syncthreads();
  }

  #pragma unroll
  for (int m = 0; m < 2; ++m)
    #pragma unroll
    for (int j = 0; j < 4; ++j) {
      const int r = row0 + wrow + m * 16 + lq * 4 + j;
      #pragma unroll
      for (int n = 0; n < 4; ++n)
        C[(size_t)r * 1024 + col0 + wcol + n * 16 + lr] = acc[m][n][j];
    }
}

// ============ 192x256 KV-GEMM, 4 fat phases (r10) + XCD swizzle +
// ============ coalesced LDS-transpose epilogue (proven r12) ===============
#define BAR()   do { __builtin_amdgcn_s_barrier(); __builtin_amdgcn_sched_barrier(0); } while (0)
#define LGKM(N) do { asm volatile("s_waitcnt lgkmcnt(" #N ")" ::: "memory"); __builtin_amdgcn_sched_barrier(0); } while (0)
#define VMC(N)  do { asm volatile("s_waitcnt vmcnt(" #N ")" ::: "memory"); __builtin_amdgcn_sched_barrier(0); } while (0)
#define PRIO1   __builtin_amdgcn_s_setprio(1)
#define PRIO0   __builtin_amdgcn_s_setprio(0)

#define LDA6(D, FB, KK, BUF)                                                  \
  { _Pragma("unroll")                                                         \
    for (int f_ = 0; f_ < 3; ++f_) {                                          \
      const int row_ = (2 * ((FB) + f_) + wm) * 16 + lr;                      \
      D[f_] = *(const bf16x8*)(As8 + (BUF) * 24576 + row_ * 128               \
               + ((((KK) * 4 + lq) ^ swz) << 4));                             \
    } }

#define LDB4(D, KK, BUF)                                                      \
  { _Pragma("unroll")                                                         \
    for (int g_ = 0; g_ < 4; ++g_) {                                          \
      const int row_ = wn * 64 + g_ * 16 + lr;                                \
      D[g_] = *(const bf16x8*)(Bs8 + (BUF) * 32768 + row_ * 128               \
               + ((((KK) * 4 + lq) ^ swz) << 4));                             \
    } }

#define MM6(AV, BV, FB)                                                       \
  { _Pragma("unroll")                                                         \
    for (int f_ = 0; f_ < 3; ++f_)                                            \
      _Pragma("unroll")                                                       \
      for (int g_ = 0; g_ < 4; ++g_)                                          \
        acc[(FB) + f_][g_] = __builtin_amdgcn_mfma_f32_16x16x32_bf16(         \
            AV[f_], BV[g_], acc[(FB) + f_][g_], 0, 0, 0); }

__global__ __launch_bounds__(512, 2)
void kv_gemm192(const short* __restrict__ A, const short* __restrict__ B,
                short* __restrict__ C,
                const int* __restrict__ f_ids, const int* __restrict__ t_ids)
{
  // single LDS pool: As = [0,24576) shorts, Bs = [24576,57344) shorts.
  // Epilogue reuses [0,49152) as a [192][256] bf16 C-tile.
  __shared__ __align__(16) short lds[57344];   // 112 KiB
  short* As = lds;
  short* Bs = lds + 24576;

  const int tid = threadIdx.x;
  const int w = tid >> 6, lane = tid & 63;
  const int wm = w >> 2, wn = w & 3;
  const int lr = lane & 15, lq = lane >> 4;

  // XCD-aware bijective swizzle: 512 blocks, 8 XCDs, 64 blocks/XCD.
  // XCD k gets by = 8k..8k+7 (all bx) -> A panels reused within one L2.
  const int bid = blockIdx.y * 8 + blockIdx.x;
  const int sid = (bid & 7) * 64 + (bid >> 3);
  const int row0 = (sid >> 3) * 192;
  const int col0 = (sid & 7) * 256;

  const int ssrc = (((tid & 7) ^ ((tid >> 3) & 7))) * 8;

  size_t a_src[3];
  #pragma unroll
  for (int c = 0; c < 3; ++c) {
    const int rr = row0 + c * 64 + (tid >> 3);
    const int bi = rr >= NB * MN;
    const int idx = rr - bi * (NB * MN);
    const int f = clampi(f_ids[idx], 0, FG - 1);
    const int q = clampi(t_ids[idx], 0, L - 1);
    a_src[c] = (size_t)((bi * FG + f) * L + q) * 1024 + ssrc;
  }
  size_t b_src[2][2];
  #pragma unroll
  for (int h = 0; h < 2; ++h)
    #pragma unroll
    for (int i = 0; i < 2; ++i)
      b_src[h][i] = (size_t)(1024 + col0 + h * 128 + ((tid + i * 512) >> 3)) * 1024 + ssrc;

  auto stgA = [&](int c, int kt, int buf) {
    gload16(A + a_src[c] + kt * 64, As + buf * 12288 + c * 4096 + tid * 8);
  };
  auto stgB = [&](int h, int kt, int buf) {
    gload16(B + b_src[h][0] + kt * 64, Bs + buf * 16384 + h * 8192 + tid * 8);
    gload16(B + b_src[h][1] + kt * 64, Bs + buf * 16384 + h * 8192 + 4096 + tid * 8);
  };

  const char* As8 = (const char*)As;
  const char* Bs8 = (const char*)Bs;
  const int swz = lane & 7;

  f32x4 acc[6][4];
  #pragma unroll
  for (int f = 0; f < 6; ++f)
    #pragma unroll
    for (int g = 0; g < 4; ++g) acc[f][g] = (f32x4){0.f, 0.f, 0.f, 0.f};

  bf16x8 avA[3], avB[3], bv0[4], bv1[4];

  // prologue: t0 full (7 ops) + t1 B,Ac0 (5 ops); wait t0 landed
  stgB(0, 0, 0); stgB(1, 0, 0); stgA(0, 0, 0); stgA(1, 0, 0); stgA(2, 0, 0);
  stgB(0, 1, 1); stgB(1, 1, 1); stgA(0, 1, 1);
  VMC(5); BAR();

  for (int I = 0; I < 7; ++I) {
    const int kA = 2 * I + 1, kB = 2 * I + 2, kC = 2 * I + 3;
    // F1: buf0 FB0, both kk; stage A1,A2 of kA -> buf1
    LDA6(avA, 0, 0, 0); LDB4(bv0, 0, 0); LDA6(avB, 0, 1, 0); LDB4(bv1, 1, 0);
    stgA(1, kA, 1); stgA(2, kA, 1);
    BAR(); LGKM(0); PRIO1; MM6(avA, bv0, 0); MM6(avB, bv1, 0); PRIO0; BAR();
    // F2: buf0 FB3; stage B+A0 of kB -> buf0
    LDA6(avA, 3, 0, 0); LDA6(avB, 3, 1, 0);
    stgB(0, kB, 0); stgB(1, kB, 0); stgA(0, kB, 0);
    BAR(); LGKM(0); PRIO1; MM6(avA, bv0, 3); MM6(avB, bv1, 3); PRIO0; VMC(5); BAR();
    // F3: buf1 FB0; stage A1,A2 of kB -> buf0
    LDA6(avA, 0, 0, 1); LDB4(bv0, 0, 1); LDA6(avB, 0, 1, 1); LDB4(bv1, 1, 1);
    stgA(1, kB, 0); stgA(2, kB, 0);
    BAR(); LGKM(0); PRIO1; MM6(avA, bv0, 0); MM6(avB, bv1, 0); PRIO0; BAR();
    // F4: buf1 FB3; stage B+A0 of kC -> buf1
    LDA6(avA, 3, 0, 1); LDA6(avB, 3, 1, 1);
    stgB(0, kC, 1); stgB(1, kC, 1); stgA(0, kC, 1);
    BAR(); LGKM(0); PRIO1; MM6(avA, bv0, 3); MM6(avB, bv1, 3); PRIO0; VMC(5); BAR();
  }

  // peeled final iteration: tiles 14 (buf0), 15 (buf1)
  {
    LDA6(avA, 0, 0, 0); LDB4(bv0, 0, 0); LDA6(avB, 0, 1, 0); LDB4(bv1, 1, 0);
    stgA(1, 15, 1); stgA(2, 15, 1);
    BAR(); LGKM(0); PRIO1; MM6(avA, bv0, 0); MM6(avB, bv1, 0); PRIO0; BAR();

    LDA6(avA, 3, 0, 0); LDA6(avB, 3, 1, 0);
    BAR(); LGKM(0); PRIO1; MM6(avA, bv0, 3); MM6(avB, bv1, 3); PRIO0; VMC(0); BAR();

    LDA6(avA, 0, 0, 1); LDB4(bv0, 0, 1); LDA6(avB, 0, 1, 1); LDB4(bv1, 1, 1);
    BAR(); LGKM(0); PRIO1; MM6(avA, bv0, 0); MM6(avB, bv1, 0); PRIO0; BAR();

    LDA6(avA, 3, 0, 1); LDA6(avB, 3, 1, 1);
    BAR(); LGKM(0); PRIO1; MM6(avA, bv0, 3); MM6(avB, bv1, 3); PRIO0;
  }

  // ---- coalesced epilogue: acc -> LDS [192][256] bf16 -> 16B/lane stores.
  // BAR(): every wave drained its LDS reads (final LGKM(0)) before arriving,
  // so the pool is free for reuse.
  BAR();
  #pragma unroll
  for (int f = 0; f < 6; ++f)
    #pragma unroll
    for (int j = 0; j < 4; ++j) {
      const int rl = (2 * f + wm) * 16 + lq * 4 + j;
      #pragma unroll
      for (int g = 0; g < 4; ++g)
        lds[rl * 256 + wn * 64 + g * 16 + lr] = f2bf(acc[f][g][j]);
    }
  LGKM(0); BAR();
  #pragma unroll
  for (int c = 0; c < 12; ++c) {
    const int flat = c * 512 + tid;          // 16B chunk index
    const int row = flat >> 5, col8 = (flat & 31) * 8;
    bf16x8 v = *(const bf16x8*)(lds + flat * 8);
    *(bf16x8*)(C + (size_t)(row0 + row) * 2048 + col0 + col8) = v;
  }
}

// ============ 64x128 m97-structure OUT-GEMM (192 blocks, proven r6) =======
__global__ __launch_bounds__(256)
void out_gemm64(const short* __restrict__ A, const short* __restrict__ B,
                float* __restrict__ C,
                const int* __restrict__ f_ids, const int* __restrict__ t_ids,
                const float* __restrict__ bias)
{
  __shared__ __align__(16) short As[4096];    // 64 x 64
  __shared__ __align__(16) short Bs[8192];    // 128 x 64

  const int tid = threadIdx.x;
  const int w = tid >> 6, lane = tid & 63;
  const int row0 = blockIdx.y * 64, col0 = blockIdx.x * 128;
  const int lr = lane & 15, lq = lane >> 4;
  const int wrow = (w >> 1) * 32, wcol = (w & 1) * 64;

  size_t asrc[2]; short* adst[2];
  #pragma unroll
  for (int c = 0; c < 2; ++c) {
    const int d = c * 256 + tid, r = d >> 3;
    const int ss = (d & 7) ^ (r & 7);
    asrc[c] = (size_t)(row0 + r) * 1024 + ss * 8;
    adst[c] = As + d * 8;
  }
  size_t bsrc[4]; short* bdst[4];
  #pragma unroll
  for (int c = 0; c < 4; ++c) {
    const int d = c * 256 + tid, r = d >> 3;
    const int ss = (d & 7) ^ (r & 7);
    bsrc[c] = (size_t)(col0 + r) * 1024 + ss * 8;
    bdst[c] = Bs + d * 8;
  }

  const char* As8 = (const char*)As;
  const char* Bs8 = (const char*)Bs;
  const int swz = lr & 7;

  f32x4 acc[2][4];
  #pragma unroll
  for (int m = 0; m < 2; ++m)
    #pragma unroll
    for (int n = 0; n < 4; ++n) acc[m][n] = (f32x4){0.f, 0.f, 0.f, 0.f};

  for (int kt = 0; kt < 16; ++kt) {
    #pragma unroll
    for (int c = 0; c < 2; ++c) gload16(A + asrc[c] + kt * 64, adst[c]);
    #pragma unroll
    for (int c = 0; c < 4; ++c) gload16(B + bsrc[c] + kt * 64, bdst[c]);
    __syncthreads();
    #pragma unroll
    for (int kk = 0; kk < 2; ++kk) {
      const int so = ((kk * 4 + lq) ^ swz) << 4;
      bf16x8 av[2], bv[4];
      #pragma unroll
      for (int m = 0; m < 2; ++m)
        av[m] = *(const bf16x8*)(As8 + (wrow + m * 16 + lr) * 128 + so);
      #pragma unroll
      for (int n = 0; n < 4; ++n)
        bv[n] = *(const bf16x8*)(Bs8 + (wcol + n * 16 + lr) * 128 + so);
      #pragma unroll
      for (int m = 0; m < 2; ++m)
        #pragma unroll
        for (int n = 0; n < 4; ++n)
          acc[m][n] = __builtin_amdgcn_mfma_f32_16x16x32_bf16(
              av[m], bv[n], acc[m][n], 0, 0, 0);
    }
    __syncthreads();
  }

  float bb[4];
  #pragma unroll
  for (int n = 0; n < 4; ++n) bb[n] = bias[col0 + wcol + n * 16 + lr];
  #pragma unroll
  for (int m = 0; m < 2; ++m)
    #pragma unroll
    for (int j = 0; j < 4; ++j) {
      const int r  = row0 + wrow + m * 16 + lq * 4 + j;
      const int bi = r >= NB;
      const int nn = r - bi * NB;
      const int bf = f_ids[nn], bt = t_ids[nn];
      const int qf = clampi(bf, 0, FG - 1), qi = clampi(bt, 0, L - 1);
      const bool valid = (bf == qf) && (bt == qi);
      const size_t obase = ((size_t)(bi * FG + qf) * L + qi) * 1024;
      #pragma unroll
      for (int n = 0; n < 4; ++n) {
        const int col = col0 + wcol + n * 16 + lr;
        C[obase + col] = valid ? (acc[m][n][j] + bb[n]) : 0.f;
      }
    }
}

// ============ attention v2 (proven r9): one block per bn ==================
__global__ __launch_bounds__(256)
void attn_kernel2(const float* __restrict__ dray,
                  const int* __restrict__ bfid, const int* __restrict__ blid,
                  const int* __restrict__ bsid,
                  const int* __restrict__ nfid, const int* __restrict__ ntid,
                  const int* __restrict__ nlid, const int* __restrict__ nsid,
                  const int* __restrict__ nmask,
                  const float* __restrict__ qbuf,
                  const short* __restrict__ kvbuf,
                  __hip_bfloat16* __restrict__ obuf)
{
  __shared__ __align__(16) short kvlds[MN * 2048];   // 32 KiB
  __shared__ float smdq[9];
  __shared__ float smdk[MN][9];
  __shared__ int   smok[MN];

  const int bn   = blockIdx.x;
  const int n    = bn % NB;
  const int tid  = threadIdx.x;
  const int w    = tid >> 6, lane = tid & 63;

  const short* kvb = kvbuf + (size_t)bn * MN * 2048;
  #pragma unroll
  for (int j = 0; j < 8; ++j)
    gload16(kvb + (j * 256 + tid) * 8, kvlds + (j * 256 + tid) * 8);

  if (tid < 9) {
    int st = clampi(bsid[n], 0, STAGES - 1);
    int f  = clampi(bfid[n], 0, FG - 1);
    int lc = clampi(blid[n], 0, L - 1);
    smdq[tid] = dray[((size_t)(st * FG + f) * L + lc) * 9 + tid];
  } else if (tid >= 64 && tid < 136) {
    const int t = tid - 64, m = t / 9, j = t - m * 9;
    const int idx = n * MN + m;
    int nst = clampi(nsid[idx], 0, STAGES - 1);
    int nfc = clampi(nfid[idx], 0, FG - 1);
    int nlc = clampi(nlid[idx], 0, L - 1);
    smdk[m][j] = dray[((size_t)(nst * FG + nfc) * L + nlc) * 9 + j];
  } else if (tid >= 192 && tid < 192 + MN) {
    const int m = tid - 192;
    const int idx = n * MN + m;
    int nf = nfid[idx], nt = ntid[idx];
    smok[m] = (nmask[idx] != 0) && nf >= 0 && nf < FG && nt >= 0 && nt < L;
  }
  __syncthreads();

  float dq[9];
  #pragma unroll
  for (int t = 0; t < 9; ++t) dq[t] = smdq[t];

  const int rr = lane & 15;

  for (int hi = 0; hi < 4; ++hi) {
    const int h = hi * 4 + w;

    const float qraw = qbuf[(size_t)bn * ADIM + h * HD + lane];
    float x0 = __shfl(qraw, rr), x1 = __shfl(qraw, 16 + rr), x2 = __shfl(qraw, 32 + rr);
    float q0 = dq[0]*x0 + dq[1]*x1 + dq[2]*x2;
    float q1 = dq[3]*x0 + dq[4]*x1 + dq[5]*x2;
    float q2 = dq[6]*x0 + dq[7]*x1 + dq[8]*x2;
    float qd = lane < 16 ? q0 : lane < 32 ? q1 : lane < 48 ? q2 : qraw;

    float s[MN], vd[MN];
    #pragma unroll
    for (int m = 0; m < MN; ++m) {
      float dk[9];
      #pragma unroll
      for (int t = 0; t < 9; ++t) dk[t] = smdk[m][t];

      float kraw = bf2f(kvlds[m * 2048 + h * HD + lane]);
      float k0 = __shfl(kraw, rr), k1 = __shfl(kraw, 16 + rr), k2 = __shfl(kraw, 32 + rr);
      float kr0 = dk[0]*k0 + dk[1]*k1 + dk[2]*k2;
      float kr1 = dk[3]*k0 + dk[4]*k1 + dk[5]*k2;
      float kr2 = dk[6]*k0 + dk[7]*k1 + dk[8]*k2;
      float kd = lane < 16 ? kr0 : lane < 32 ? kr1 : lane < 48 ? kr2 : kraw;

      float p = qd * kd;
      #pragma unroll
      for (int off = 32; off; off >>= 1) p += __shfl_xor(p, off);
      s[m] = p;

      float vraw = bf2f(kvlds[m * 2048 + 1024 + h * HD + lane]);
      float v0 = __shfl(vraw, rr), v1 = __shfl(vraw, 16 + rr), v2 = __shfl(vraw, 32 + rr);
      float vr0 = dk[0]*v0 + dk[1]*v1 + dk[2]*v2;
      float vr1 = dk[3]*v0 + dk[4]*v1 + dk[5]*v2;
      float vr2 = dk[6]*v0 + dk[7]*v1 + dk[8]*v2;
      vd[m] = lane < 16 ? vr0 : lane < 32 ? vr1 : lane < 48 ? vr2 : vraw;
    }

    float mx = -INFINITY;
    #pragma unroll
    for (int m = 0; m < MN; ++m) {
      s[m] = smok[m] ? s[m] * SCALE : -INFINITY;
      mx = fmaxf(mx, s[m]);
    }
    float den = 0.f;
    #pragma unroll
    for (int m = 0; m < MN; ++m) { s[m] = expf(s[m] - mx); den += s[m]; }
    float inv = 1.0f / den;

    float od = 0.f;
    #pragma unroll
    for (int m = 0; m < MN; ++m) od += s[m] * vd[m];
    od *= inv;

    float y0 = __shfl(od, rr), y1 = __shfl(od, 16 + rr), y2 = __shfl(od, 32 + rr);
    float t0 = dq[0]*y0 + dq[3]*y1 + dq[6]*y2;
    float t1 = dq[1]*y0 + dq[4]*y1 + dq[7]*y2;
    float t2 = dq[2]*y0 + dq[5]*y1 + dq[8]*y2;
    float outd = lane < 16 ? t0 : lane < 32 ? t1 : lane < 48 ? t2 : od;

    obuf[(size_t)bn * ADIM + h * HD + lane] = __float2bfloat16(outd);
  }
}

extern "C" void kernel_launch(void* const* d_in, const int* in_sizes, int n_in,
                              void* d_out, int out_size, void* d_ws, size_t ws_size,
                              hipStream_t stream) {
  const float* x     = (const float*)d_in[0];
  const float* qkv_w = (const float*)d_in[1];
  const float* out_w = (const float*)d_in[2];
  const float* out_b = (const float*)d_in[3];
  const float* dray  = (const float*)d_in[4];
  const int* bfid  = (const int*)d_in[5];
  const int* btid  = (const int*)d_in[6];
  const int* blid  = (const int*)d_in[7];
  const int* bsid  = (const int*)d_in[8];
  const int* nfid  = (const int*)d_in[9];
  const int* ntid  = (const int*)d_in[10];
  const int* nlid  = (const int*)d_in[11];
  const int* nsid  = (const int*)d_in[12];
  const int* nmask = (const int*)d_in[13];

  char* ws = (char*)d_ws;
  short* xb    = (short*)(ws);                  // 12288*1024 bf16 = 25165824 B
  short* qwT   = (short*)(ws + 25165824);       // 3072*1024  bf16 =  6291456 B
  short* owT   = (short*)(ws + 31457280);       // 1024*1024  bf16 =  2097152 B
  float* qbuf  = (float*)(ws + 33554432);       // 1536*1024  f32  =  6291456 B
  short* kvbuf = (short*)(ws + 39845888);       // 12288*2048 bf16 = 50331648 B
  short* obuf  = (short*)(ws + 90177536);       // 1536*1024  bf16 =  3145728 B

  // zero d_out + x->bf16 + both weight transposes in one dispatch
  prep_kernel<<<16384, 256, 0, stream>>>(x, xb, (float*)d_out,
                                         qkv_w, qwT, out_w, owT);

  // Q projection: 1536 x 1024 x 1024 (64x128 tiles, 192 blocks)
  q_gemm64<<<dim3(8, 24), 256, 0, stream>>>(xb, qwT, qbuf, bfid, btid);
  // KV projection: 12288 x 2048 x 1024 (192x256, 4 fat phases, 512 blocks,
  // XCD swizzle, coalesced epilogue)
  kv_gemm192<<<dim3(8, 64), 512, 0, stream>>>(xb, qwT, kvbuf, nfid, ntid);
  // fused rotations + attention (one block per bn, LDS-staged)
  attn_kernel2<<<1536, 256, 0, stream>>>(dray, bfid, blid, bsid,
                                         nfid, ntid, nlid, nsid, nmask,
                                         qbuf, kvbuf,
                                         (__hip_bfloat16*)obuf);
  // output projection + bias + valid mask + scatter: 1536 x 1024 x 1024
  out_gemm64<<<dim3(8, 24), 256, 0, stream>>>(obuf, owT, (float*)d_out,
                                              bfid, btid, out_b);
}

// Round 15
// 148.224 us; speedup vs baseline: 1.0139x; 1.0139x over previous
//
#include <hip/hip_runtime.h>
#include <hip/hip_bf16.h>
#include <cstddef>

#define FG 6
#define L 1024
#define NB 768
#define MN 8
#define H 16
#define HD 64
#define ADIM 1024
#define STAGES 4
#define SCALE 0.125f

typedef __attribute__((ext_vector_type(8))) short bf16x8;
typedef __attribute__((ext_vector_type(4))) float f32x4;
typedef __attribute__((address_space(3))) short lds_short_t;
typedef const __attribute__((address_space(1))) short g_short_t;

__device__ __forceinline__ int clampi(int v, int lo, int hi) {
  return v < lo ? lo : (v > hi ? hi : v);
}

__device__ __forceinline__ short f2bf(float f) {
  __hip_bfloat16 h = __float2bfloat16(f);
  return *reinterpret_cast<short*>(&h);
}

__device__ __forceinline__ float bf2f(short s) {
  __hip_bfloat16 h = *reinterpret_cast<__hip_bfloat16*>(&s);
  return __bfloat162float(h);
}

__device__ __forceinline__ void gload16(const short* g, short* l) {
  __builtin_amdgcn_global_load_lds((g_short_t*)g, (lds_short_t*)l, 16, 0, 0);
}

// One dispatch: blocks [0,12288) zero d_out (blocks <6144 also convert x to
// bf16); blocks [12288,15360) transpose qkv_w; [15360,16384) transpose out_w.
__global__ __launch_bounds__(256)
void prep_kernel(const float* __restrict__ x, short* __restrict__ xb,
                 float* __restrict__ zout,
                 const float* __restrict__ qkv_w, short* __restrict__ qwT,
                 const float* __restrict__ out_w, short* __restrict__ owT) {
  const int b = blockIdx.x;
  if (b < 12288) {
    const size_t zi = ((size_t)b * 256 + threadIdx.x) * 4;
    *(float4*)(zout + zi) = (float4){0.f, 0.f, 0.f, 0.f};
    if (b >= 6144) return;
    size_t i = ((size_t)b * 256 + threadIdx.x) * 8;
    float4 a = *(const float4*)(x + i);
    float4 c = *(const float4*)(x + i + 4);
    bf16x8 v;
    v[0] = f2bf(a.x); v[1] = f2bf(a.y); v[2] = f2bf(a.z); v[3] = f2bf(a.w);
    v[4] = f2bf(c.x); v[5] = f2bf(c.y); v[6] = f2bf(c.z); v[7] = f2bf(c.w);
    *(bf16x8*)(xb + i) = v;
    return;
  }
  int t = b - 12288;
  const float* in; short* out; int N, n0, k0;
  if (t < 3072) { in = qkv_w; out = qwT; N = 3072; n0 = (t % 96) * 32; k0 = (t / 96) * 32; }
  else { t -= 3072; in = out_w; out = owT; N = 1024; n0 = (t % 32) * 32; k0 = (t / 32) * 32; }
  __shared__ float tile[32][33];
  const int tx = threadIdx.x & 31, ty = threadIdx.x >> 5;
  #pragma unroll
  for (int i = 0; i < 4; ++i)
    tile[ty + i * 8][tx] = in[(size_t)(k0 + ty + i * 8) * N + n0 + tx];
  __syncthreads();
  #pragma unroll
  for (int i = 0; i < 4; ++i)
    out[(size_t)(n0 + ty + i * 8) * 1024 + k0 + tx] =
        f2bf(tile[tx][ty + i * 8]);
}

// ============ 64x128 m97-structure Q-GEMM (192 blocks, proven r8) =========
__global__ __launch_bounds__(256)
void q_gemm64(const short* __restrict__ A, const short* __restrict__ B,
              float* __restrict__ C,
              const int* __restrict__ f_ids, const int* __restrict__ t_ids)
{
  __shared__ __align__(16) short As[4096];    // 64 x 64
  __shared__ __align__(16) short Bs[8192];    // 128 x 64

  const int tid = threadIdx.x;
  const int w = tid >> 6, lane = tid & 63;
  const int row0 = blockIdx.y * 64, col0 = blockIdx.x * 128;
  const int lr = lane & 15, lq = lane >> 4;
  const int wrow = (w >> 1) * 32, wcol = (w & 1) * 64;

  size_t asrc[2]; short* adst[2];
  #pragma unroll
  for (int c = 0; c < 2; ++c) {
    const int d = c * 256 + tid, r = d >> 3;
    const int ss = (d & 7) ^ (r & 7);
    const int rr = row0 + r;
    const int bi = rr >= NB;
    const int idx = rr - bi * NB;
    const int f = clampi(f_ids[idx], 0, FG - 1);
    const int q = clampi(t_ids[idx], 0, L - 1);
    asrc[c] = (size_t)((bi * FG + f) * L + q) * 1024 + ss * 8;
    adst[c] = As + d * 8;
  }
  size_t bsrc[4]; short* bdst[4];
  #pragma unroll
  for (int c = 0; c < 4; ++c) {
    const int d = c * 256 + tid, r = d >> 3;
    const int ss = (d & 7) ^ (r & 7);
    bsrc[c] = (size_t)(col0 + r) * 1024 + ss * 8;
    bdst[c] = Bs + d * 8;
  }

  const char* As8 = (const char*)As;
  const char* Bs8 = (const char*)Bs;
  const int swz = lr & 7;

  f32x4 acc[2][4];
  #pragma unroll
  for (int m = 0; m < 2; ++m)
    #pragma unroll
    for (int n = 0; n < 4; ++n) acc[m][n] = (f32x4){0.f, 0.f, 0.f, 0.f};

  for (int kt = 0; kt < 16; ++kt) {
    #pragma unroll
    for (int c = 0; c < 2; ++c) gload16(A + asrc[c] + kt * 64, adst[c]);
    #pragma unroll
    for (int c = 0; c < 4; ++c) gload16(B + bsrc[c] + kt * 64, bdst[c]);
    __syncthreads();
    #pragma unroll
    for (int kk = 0; kk < 2; ++kk) {
      const int so = ((kk * 4 + lq) ^ swz) << 4;
      bf16x8 av[2], bv[4];
      #pragma unroll
      for (int m = 0; m < 2; ++m)
        av[m] = *(const bf16x8*)(As8 + (wrow + m * 16 + lr) * 128 + so);
      #pragma unroll
      for (int n = 0; n < 4; ++n)
        bv[n] = *(const bf16x8*)(Bs8 + (wcol + n * 16 + lr) * 128 + so);
      #pragma unroll
      for (int m = 0; m < 2; ++m)
        #pragma unroll
        for (int n = 0; n < 4; ++n)
          acc[m][n] = __builtin_amdgcn_mfma_f32_16x16x32_bf16(
              av[m], bv[n], acc[m][n], 0, 0, 0);
    }
    __syncthreads();
  }

  #pragma unroll
  for (int m = 0; m < 2; ++m)
    #pragma unroll
    for (int j = 0; j < 4; ++j) {
      const int r = row0 + wrow + m * 16 + lq * 4 + j;
      #pragma unroll
      for (int n = 0; n < 4; ++n)
        C[(size_t)r * 1024 + col0 + wcol + n * 16 + lr] = acc[m][n][j];
    }
}

// ============ 192x128 KV-GEMM: r12 template at 80 KiB -> 2 blocks/CU ======
// Same 4-phase skeleton, staging structure (A=3 ops, B=2 ops/tile), region
// disjointness and counted-vmcnt ledger as the r12/r14-verified kernel; only
// geometry changed (N 256->128, 8 waves as 4Mx2N, acc[3][4], VMC(5)->VMC(3)).
// LDS 48K(A dbuf) + 32K(B dbuf) = 80K -> 2 blocks/CU; 1024 blocks = 2 rounds.
#define BAR()   do { __builtin_amdgcn_s_barrier(); __builtin_amdgcn_sched_barrier(0); } while (0)
#define LGKM(N) do { asm volatile("s_waitcnt lgkmcnt(" #N ")" ::: "memory"); __builtin_amdgcn_sched_barrier(0); } while (0)
#define VMC(N)  do { asm volatile("s_waitcnt vmcnt(" #N ")" ::: "memory"); __builtin_amdgcn_sched_barrier(0); } while (0)
#define PRIO1   __builtin_amdgcn_s_setprio(1)
#define PRIO0   __builtin_amdgcn_s_setprio(0)

// one A fragment: row-group fr (0..2), k-half KK, buffer BUF
#define LDAF(D, FR, KK, BUF)                                                  \
  D = *(const bf16x8*)(As8 + (BUF) * 24576 +                                  \
        ((4 * (FR) + wm) * 16 + lr) * 128 + ((((KK) * 4 + lq) ^ swz) << 4));

#define LDBF(D, KK, BUF)                                                      \
  { _Pragma("unroll")                                                         \
    for (int g_ = 0; g_ < 4; ++g_)                                            \
      D[g_] = *(const bf16x8*)(Bs8 + (BUF) * 16384 +                          \
                (wn * 64 + g_ * 16 + lr) * 128 +                              \
                ((((KK) * 4 + lq) ^ swz) << 4)); }

#define MMF(AV, BV, FR)                                                       \
  { _Pragma("unroll")                                                         \
    for (int g_ = 0; g_ < 4; ++g_)                                            \
      acc[FR][g_] = __builtin_amdgcn_mfma_f32_16x16x32_bf16(                  \
          AV, BV[g_], acc[FR][g_], 0, 0, 0); }

__global__ __launch_bounds__(512, 4)
void kv_gemm192(const short* __restrict__ A, const short* __restrict__ B,
                short* __restrict__ C,
                const int* __restrict__ f_ids, const int* __restrict__ t_ids)
{
  __shared__ __align__(16) short As[24576];   // 2 x 192 x 64 = 48 KiB
  __shared__ __align__(16) short Bs[16384];   // 2 x 128 x 64 = 32 KiB

  const int tid = threadIdx.x;
  const int w = tid >> 6, lane = tid & 63;
  const int wm = w >> 1;           // 0..3 (M group)
  const int wn = w & 1;            // 0..1 (N group)
  const int lr = lane & 15, lq = lane >> 4;

  // XCD-aware bijective swizzle: 1024 blocks, 8 XCDs, 128 blocks/XCD.
  // XCD k gets row panels k*8..k*8+7 across all 16 cols -> 16x A-panel reuse.
  const int bid = blockIdx.y * 16 + blockIdx.x;
  const int sid = (bid & 7) * 128 + (bid >> 3);
  const int row0 = (sid >> 4) * 192;
  const int col0 = (sid & 15) * 128;

  const int ssrc = (((tid & 7) ^ ((tid >> 3) & 7))) * 8;

  int a_src[3];
  #pragma unroll
  for (int c = 0; c < 3; ++c) {
    const int rr = row0 + c * 64 + (tid >> 3);
    const int bi = rr >= NB * MN;
    const int idx = rr - bi * (NB * MN);
    const int f = clampi(f_ids[idx], 0, FG - 1);
    const int q = clampi(t_ids[idx], 0, L - 1);
    a_src[c] = ((bi * FG + f) * L + q) * 1024 + ssrc;
  }
  int b_src[2];
  #pragma unroll
  for (int i = 0; i < 2; ++i)
    b_src[i] = (1024 + col0 + (tid >> 3) + i * 64) * 1024 + ssrc;

  auto stgA = [&](int c, int kt, int buf) {
    gload16(A + a_src[c] + kt * 64, As + buf * 12288 + c * 4096 + tid * 8);
  };
  auto stgB = [&](int kt, int buf) {
    gload16(B + b_src[0] + kt * 64, Bs + buf * 8192 + tid * 8);
    gload16(B + b_src[1] + kt * 64, Bs + buf * 8192 + 4096 + tid * 8);
  };

  const char* As8 = (const char*)As;
  const char* Bs8 = (const char*)Bs;
  const int swz = lane & 7;

  f32x4 acc[3][4];
  #pragma unroll
  for (int f = 0; f < 3; ++f)
    #pragma unroll
    for (int g = 0; g < 4; ++g) acc[f][g] = (f32x4){0.f, 0.f, 0.f, 0.f};

  bf16x8 a00, a10, a01, a11, a20, a21, bv0[4], bv1[4];

  // prologue: t0 full (5 ops) + t1 B,A0 (3 ops); wait t0 landed
  stgB(0, 0); stgA(0, 0, 0); stgA(1, 0, 0); stgA(2, 0, 0);
  stgB(1, 1); stgA(0, 1, 1);
  VMC(3); BAR();

  for (int I = 0; I < 7; ++I) {
    const int kA = 2 * I + 1, kB = 2 * I + 2, kC = 2 * I + 3;
    // F1: buf0 fr0,fr1 both kk (12 reads, 16 MFMA); stage A1,A2 of kA->buf1
    LDAF(a00, 0, 0, 0); LDAF(a10, 1, 0, 0); LDBF(bv0, 0, 0);
    LDAF(a01, 0, 1, 0); LDAF(a11, 1, 1, 0); LDBF(bv1, 1, 0);
    stgA(1, kA, 1); stgA(2, kA, 1);
    BAR(); LGKM(0);
    PRIO1; MMF(a00, bv0, 0); MMF(a10, bv0, 1); MMF(a01, bv1, 0); MMF(a11, bv1, 1); PRIO0;
    BAR();
    // F2: buf0 fr2 both kk (2 reads, 8 MFMA); stage B+A0 of kB->buf0
    //     (buf0 B fully read in F1; A chunk0 = fr0 rows, read in F1)
    LDAF(a20, 2, 0, 0); LDAF(a21, 2, 1, 0);
    stgB(kB, 0); stgA(0, kB, 0);
    BAR(); LGKM(0);
    PRIO1; MMF(a20, bv0, 2); MMF(a21, bv1, 2); PRIO0;
    VMC(3); BAR();
    // F3: buf1 fr0,fr1; stage A1,A2 of kB->buf0
    LDAF(a00, 0, 0, 1); LDAF(a10, 1, 0, 1); LDBF(bv0, 0, 1);
    LDAF(a01, 0, 1, 1); LDAF(a11, 1, 1, 1); LDBF(bv1, 1, 1);
    stgA(1, kB, 0); stgA(2, kB, 0);
    BAR(); LGKM(0);
    PRIO1; MMF(a00, bv0, 0); MMF(a10, bv0, 1); MMF(a01, bv1, 0); MMF(a11, bv1, 1); PRIO0;
    BAR();
    // F4: buf1 fr2; stage B+A0 of kC->buf1
    LDAF(a20, 2, 0, 1); LDAF(a21, 2, 1, 1);
    stgB(kC, 1); stgA(0, kC, 1);
    BAR(); LGKM(0);
    PRIO1; MMF(a20, bv0, 2); MMF(a21, bv1, 2); PRIO0;
    VMC(3); BAR();
  }

  // peeled final iteration: tiles 14 (buf0), 15 (buf1); no staging past t15
  {
    LDAF(a00, 0, 0, 0); LDAF(a10, 1, 0, 0); LDBF(bv0, 0, 0);
    LDAF(a01, 0, 1, 0); LDAF(a11, 1, 1, 0); LDBF(bv1, 1, 0);
    stgA(1, 15, 1); stgA(2, 15, 1);
    BAR(); LGKM(0);
    PRIO1; MMF(a00, bv0, 0); MMF(a10, bv0, 1); MMF(a01, bv1, 0); MMF(a11, bv1, 1); PRIO0;
    BAR();

    LDAF(a20, 2, 0, 0); LDAF(a21, 2, 1, 0);
    BAR(); LGKM(0);
    PRIO1; MMF(a20, bv0, 2); MMF(a21, bv1, 2); PRIO0;
    VMC(0); BAR();

    LDAF(a00, 0, 0, 1); LDAF(a10, 1, 0, 1); LDBF(bv0, 0, 1);
    LDAF(a01, 0, 1, 1); LDAF(a11, 1, 1, 1); LDBF(bv1, 1, 1);
    BAR(); LGKM(0);
    PRIO1; MMF(a00, bv0, 0); MMF(a10, bv0, 1); MMF(a01, bv1, 0); MMF(a11, bv1, 1); PRIO0;
    BAR();

    LDAF(a20, 2, 0, 1); LDAF(a21, 2, 1, 1);
    BAR(); LGKM(0);
    PRIO1; MMF(a20, bv0, 2); MMF(a21, bv1, 2); PRIO0;
  }

  // epilogue: direct bf16 stores (r10-proven), ldc 2048
  #pragma unroll
  for (int f = 0; f < 3; ++f) {
    #pragma unroll
    for (int j = 0; j < 4; ++j) {
      const int r = row0 + (4 * f + wm) * 16 + lq * 4 + j;
      short* cp = C + (size_t)r * 2048 + col0 + wn * 64 + lr;
      #pragma unroll
      for (int g = 0; g < 4; ++g)
        cp[g * 16] = f2bf(acc[f][g][j]);
    }
  }
}

// ============ 64x128 m97-structure OUT-GEMM (192 blocks, proven r6) =======
__global__ __launch_bounds__(256)
void out_gemm64(const short* __restrict__ A, const short* __restrict__ B,
                float* __restrict__ C,
                const int* __restrict__ f_ids, const int* __restrict__ t_ids,
                const float* __restrict__ bias)
{
  __shared__ __align__(16) short As[4096];    // 64 x 64
  __shared__ __align__(16) short Bs[8192];    // 128 x 64

  const int tid = threadIdx.x;
  const int w = tid >> 6, lane = tid & 63;
  const int row0 = blockIdx.y * 64, col0 = blockIdx.x * 128;
  const int lr = lane & 15, lq = lane >> 4;
  const int wrow = (w >> 1) * 32, wcol = (w & 1) * 64;

  size_t asrc[2]; short* adst[2];
  #pragma unroll
  for (int c = 0; c < 2; ++c) {
    const int d = c * 256 + tid, r = d >> 3;
    const int ss = (d & 7) ^ (r & 7);
    asrc[c] = (size_t)(row0 + r) * 1024 + ss * 8;
    adst[c] = As + d * 8;
  }
  size_t bsrc[4]; short* bdst[4];
  #pragma unroll
  for (int c = 0; c < 4; ++c) {
    const int d = c * 256 + tid, r = d >> 3;
    const int ss = (d & 7) ^ (r & 7);
    bsrc[c] = (size_t)(col0 + r) * 1024 + ss * 8;
    bdst[c] = Bs + d * 8;
  }

  const char* As8 = (const char*)As;
  const char* Bs8 = (const char*)Bs;
  const int swz = lr & 7;

  f32x4 acc[2][4];
  #pragma unroll
  for (int m = 0; m < 2; ++m)
    #pragma unroll
    for (int n = 0; n < 4; ++n) acc[m][n] = (f32x4){0.f, 0.f, 0.f, 0.f};

  for (int kt = 0; kt < 16; ++kt) {
    #pragma unroll
    for (int c = 0; c < 2; ++c) gload16(A + asrc[c] + kt * 64, adst[c]);
    #pragma unroll
    for (int c = 0; c < 4; ++c) gload16(B + bsrc[c] + kt * 64, bdst[c]);
    __syncthreads();
    #pragma unroll
    for (int kk = 0; kk < 2; ++kk) {
      const int so = ((kk * 4 + lq) ^ swz) << 4;
      bf16x8 av[2], bv[4];
      #pragma unroll
      for (int m = 0; m < 2; ++m)
        av[m] = *(const bf16x8*)(As8 + (wrow + m * 16 + lr) * 128 + so);
      #pragma unroll
      for (int n = 0; n < 4; ++n)
        bv[n] = *(const bf16x8*)(Bs8 + (wcol + n * 16 + lr) * 128 + so);
      #pragma unroll
      for (int m = 0; m < 2; ++m)
        #pragma unroll
        for (int n = 0; n < 4; ++n)
          acc[m][n] = __builtin_amdgcn_mfma_f32_16x16x32_bf16(
              av[m], bv[n], acc[m][n], 0, 0, 0);
    }
    __syncthreads();
  }

  float bb[4];
  #pragma unroll
  for (int n = 0; n < 4; ++n) bb[n] = bias[col0 + wcol + n * 16 + lr];
  #pragma unroll
  for (int m = 0; m < 2; ++m)
    #pragma unroll
    for (int j = 0; j < 4; ++j) {
      const int r  = row0 + wrow + m * 16 + lq * 4 + j;
      const int bi = r >= NB;
      const int nn = r - bi * NB;
      const int bf = f_ids[nn], bt = t_ids[nn];
      const int qf = clampi(bf, 0, FG - 1), qi = clampi(bt, 0, L - 1);
      const bool valid = (bf == qf) && (bt == qi);
      const size_t obase = ((size_t)(bi * FG + qf) * L + qi) * 1024;
      #pragma unroll
      for (int n = 0; n < 4; ++n) {
        const int col = col0 + wcol + n * 16 + lr;
        C[obase + col] = valid ? (acc[m][n][j] + bb[n]) : 0.f;
      }
    }
}

// ============ attention v2 (proven r9): one block per bn ==================
__global__ __launch_bounds__(256)
void attn_kernel2(const float* __restrict__ dray,
                  const int* __restrict__ bfid, const int* __restrict__ blid,
                  const int* __restrict__ bsid,
                  const int* __restrict__ nfid, const int* __restrict__ ntid,
                  const int* __restrict__ nlid, const int* __restrict__ nsid,
                  const int* __restrict__ nmask,
                  const float* __restrict__ qbuf,
                  const short* __restrict__ kvbuf,
                  __hip_bfloat16* __restrict__ obuf)
{
  __shared__ __align__(16) short kvlds[MN * 2048];   // 32 KiB
  __shared__ float smdq[9];
  __shared__ float smdk[MN][9];
  __shared__ int   smok[MN];

  const int bn   = blockIdx.x;
  const int n    = bn % NB;
  const int tid  = threadIdx.x;
  const int w    = tid >> 6, lane = tid & 63;

  const short* kvb = kvbuf + (size_t)bn * MN * 2048;
  #pragma unroll
  for (int j = 0; j < 8; ++j)
    gload16(kvb + (j * 256 + tid) * 8, kvlds + (j * 256 + tid) * 8);

  if (tid < 9) {
    int st = clampi(bsid[n], 0, STAGES - 1);
    int f  = clampi(bfid[n], 0, FG - 1);
    int lc = clampi(blid[n], 0, L - 1);
    smdq[tid] = dray[((size_t)(st * FG + f) * L + lc) * 9 + tid];
  } else if (tid >= 64 && tid < 136) {
    const int t = tid - 64, m = t / 9, j = t - m * 9;
    const int idx = n * MN + m;
    int nst = clampi(nsid[idx], 0, STAGES - 1);
    int nfc = clampi(nfid[idx], 0, FG - 1);
    int nlc = clampi(nlid[idx], 0, L - 1);
    smdk[m][j] = dray[((size_t)(nst * FG + nfc) * L + nlc) * 9 + j];
  } else if (tid >= 192 && tid < 192 + MN) {
    const int m = tid - 192;
    const int idx = n * MN + m;
    int nf = nfid[idx], nt = ntid[idx];
    smok[m] = (nmask[idx] != 0) && nf >= 0 && nf < FG && nt >= 0 && nt < L;
  }
  __syncthreads();

  float dq[9];
  #pragma unroll
  for (int t = 0; t < 9; ++t) dq[t] = smdq[t];

  const int rr = lane & 15;

  for (int hi = 0; hi < 4; ++hi) {
    const int h = hi * 4 + w;

    const float qraw = qbuf[(size_t)bn * ADIM + h * HD + lane];
    float x0 = __shfl(qraw, rr), x1 = __shfl(qraw, 16 + rr), x2 = __shfl(qraw, 32 + rr);
    float q0 = dq[0]*x0 + dq[1]*x1 + dq[2]*x2;
    float q1 = dq[3]*x0 + dq[4]*x1 + dq[5]*x2;
    float q2 = dq[6]*x0 + dq[7]*x1 + dq[8]*x2;
    float qd = lane < 16 ? q0 : lane < 32 ? q1 : lane < 48 ? q2 : qraw;

    float s[MN], vd[MN];
    #pragma unroll
    for (int m = 0; m < MN; ++m) {
      float dk[9];
      #pragma unroll
      for (int t = 0; t < 9; ++t) dk[t] = smdk[m][t];

      float kraw = bf2f(kvlds[m * 2048 + h * HD + lane]);
      float k0 = __shfl(kraw, rr), k1 = __shfl(kraw, 16 + rr), k2 = __shfl(kraw, 32 + rr);
      float kr0 = dk[0]*k0 + dk[1]*k1 + dk[2]*k2;
      float kr1 = dk[3]*k0 + dk[4]*k1 + dk[5]*k2;
      float kr2 = dk[6]*k0 + dk[7]*k1 + dk[8]*k2;
      float kd = lane < 16 ? kr0 : lane < 32 ? kr1 : lane < 48 ? kr2 : kraw;

      float p = qd * kd;
      #pragma unroll
      for (int off = 32; off; off >>= 1) p += __shfl_xor(p, off);
      s[m] = p;

      float vraw = bf2f(kvlds[m * 2048 + 1024 + h * HD + lane]);
      float v0 = __shfl(vraw, rr), v1 = __shfl(vraw, 16 + rr), v2 = __shfl(vraw, 32 + rr);
      float vr0 = dk[0]*v0 + dk[1]*v1 + dk[2]*v2;
      float vr1 = dk[3]*v0 + dk[4]*v1 + dk[5]*v2;
      float vr2 = dk[6]*v0 + dk[7]*v1 + dk[8]*v2;
      vd[m] = lane < 16 ? vr0 : lane < 32 ? vr1 : lane < 48 ? vr2 : vraw;
    }

    float mx = -INFINITY;
    #pragma unroll
    for (int m = 0; m < MN; ++m) {
      s[m] = smok[m] ? s[m] * SCALE : -INFINITY;
      mx = fmaxf(mx, s[m]);
    }
    float den = 0.f;
    #pragma unroll
    for (int m = 0; m < MN; ++m) { s[m] = expf(s[m] - mx); den += s[m]; }
    float inv = 1.0f / den;

    float od = 0.f;
    #pragma unroll
    for (int m = 0; m < MN; ++m) od += s[m] * vd[m];
    od *= inv;

    float y0 = __shfl(od, rr), y1 = __shfl(od, 16 + rr), y2 = __shfl(od, 32 + rr);
    float t0 = dq[0]*y0 + dq[3]*y1 + dq[6]*y2;
    float t1 = dq[1]*y0 + dq[4]*y1 + dq[7]*y2;
    float t2 = dq[2]*y0 + dq[5]*y1 + dq[8]*y2;
    float outd = lane < 16 ? t0 : lane < 32 ? t1 : lane < 48 ? t2 : od;

    obuf[(size_t)bn * ADIM + h * HD + lane] = __float2bfloat16(outd);
  }
}

extern "C" void kernel_launch(void* const* d_in, const int* in_sizes, int n_in,
                              void* d_out, int out_size, void* d_ws, size_t ws_size,
                              hipStream_t stream) {
  const float* x     = (const float*)d_in[0];
  const float* qkv_w = (const float*)d_in[1];
  const float* out_w = (const float*)d_in[2];
  const float* out_b = (const float*)d_in[3];
  const float* dray  = (const float*)d_in[4];
  const int* bfid  = (const int*)d_in[5];
  const int* btid  = (const int*)d_in[6];
  const int* blid  = (const int*)d_in[7];
  const int* bsid  = (const int*)d_in[8];
  const int* nfid  = (const int*)d_in[9];
  const int* ntid  = (const int*)d_in[10];
  const int* nlid  = (const int*)d_in[11];
  const int* nsid  = (const int*)d_in[12];
  const int* nmask = (const int*)d_in[13];

  char* ws = (char*)d_ws;
  short* xb    = (short*)(ws);                  // 12288*1024 bf16 = 25165824 B
  short* qwT   = (short*)(ws + 25165824);       // 3072*1024  bf16 =  6291456 B
  short* owT   = (short*)(ws + 31457280);       // 1024*1024  bf16 =  2097152 B
  float* qbuf  = (float*)(ws + 33554432);       // 1536*1024  f32  =  6291456 B
  short* kvbuf = (short*)(ws + 39845888);       // 12288*2048 bf16 = 50331648 B
  short* obuf  = (short*)(ws + 90177536);       // 1536*1024  bf16 =  3145728 B

  // zero d_out + x->bf16 + both weight transposes in one dispatch
  prep_kernel<<<16384, 256, 0, stream>>>(x, xb, (float*)d_out,
                                         qkv_w, qwT, out_w, owT);

  // Q projection: 1536 x 1024 x 1024 (64x128 tiles, 192 blocks)
  q_gemm64<<<dim3(8, 24), 256, 0, stream>>>(xb, qwT, qbuf, bfid, btid);
  // KV projection: 12288 x 2048 x 1024 (192x128, 80 KiB -> 2 blocks/CU,
  // 1024 blocks = 2 rounds, XCD swizzle)
  kv_gemm192<<<dim3(16, 64), 512, 0, stream>>>(xb, qwT, kvbuf, nfid, ntid);
  // fused rotations + attention (one block per bn, LDS-staged)
  attn_kernel2<<<1536, 256, 0, stream>>>(dray, bfid, blid, bsid,
                                         nfid, ntid, nlid, nsid, nmask,
                                         qbuf, kvbuf,
                                         (__hip_bfloat16*)obuf);
  // output projection + bias + valid mask + scatter: 1536 x 1024 x 1024
  out_gemm64<<<dim3(8, 24), 256, 0, stream>>>(obuf, owT, (float*)d_out,
                                              bfid, btid, out_b);
}